// Round 1
// baseline (151.458 us; speedup 1.0000x reference)
//
#include <hip/hip_runtime.h>
#include <math.h>

#define B 4
#define T 4096
#define H 2048

// ---------------------------------------------------------------------------
// Phase 1: per-chunk local scan from zero state.
// grid: B * NC * (H/256) blocks of 256 threads. Thread = (b, chunk c, h).
// Writes locals at [(c*B + b)*H + h] (coalesced in h).
// ---------------------------------------------------------------------------
__global__ void wkv_local_kernel(const float* __restrict__ k,
                                 const float* __restrict__ v,
                                 const float* __restrict__ time_decay,
                                 float* __restrict__ loc_a,
                                 float* __restrict__ loc_b,
                                 int C, int NC) {
    const int HB = H / 256;
    int hb = blockIdx.x % HB;
    int c  = (blockIdx.x / HB) % NC;
    int b  = blockIdx.x / (HB * NC);
    int h  = hb * 256 + threadIdx.x;

    float ew = expf(-expf(time_decay[h]));

    const float* kp = k + ((size_t)b * T + (size_t)c * C) * H + h;
    const float* vp = v + ((size_t)b * T + (size_t)c * C) * H + h;

    float a = 0.0f, bb = 0.0f;
    for (int i = 0; i < C; ++i) {
        float kk = kp[(size_t)i * H];
        float vv = vp[(size_t)i * H];
        float ek = expf(kk);
        a  = ew * a  + ek * vv;
        bb = ew * bb + ek;
    }
    size_t o = ((size_t)c * B + b) * H + h;
    loc_a[o] = a;
    loc_b[o] = bb;
}

// ---------------------------------------------------------------------------
// Phase 2: sequential carry scan across chunks, per (b,h).
// Overwrites locals in place with EXCLUSIVE carries; writes final a,b to out.
// grid: B*H/256 blocks of 256 threads.
// ---------------------------------------------------------------------------
__global__ void wkv_carry_kernel(const float* __restrict__ time_decay,
                                 float* __restrict__ loc_a,
                                 float* __restrict__ loc_b,
                                 float* __restrict__ out,
                                 int C, int NC) {
    int idx = blockIdx.x * 256 + threadIdx.x;   // 0 .. B*H-1
    int b = idx / H;
    int h = idx % H;

    float ew  = expf(-expf(time_decay[h]));
    float ewC = powf(ew, (float)C);

    float Sa = 0.0f, Sb = 0.0f;
    for (int c = 0; c < NC; ++c) {
        size_t o = ((size_t)c * B + b) * H + h;
        float la = loc_a[o];
        float lb = loc_b[o];
        loc_a[o] = Sa;         // exclusive carry for chunk c
        loc_b[o] = Sb;
        Sa = ewC * Sa + la;
        Sb = ewC * Sb + lb;
    }
    // final states (outputs 1 and 2)
    out[(size_t)B * T * H + (size_t)b * H + h] = Sa;
    out[(size_t)B * T * H + (size_t)B * H + (size_t)b * H + h] = Sb;
}

// ---------------------------------------------------------------------------
// Phase 3: replay each chunk from its exclusive carry, emit wkv outputs.
// Same decomposition as phase 1.
// ---------------------------------------------------------------------------
__global__ void wkv_emit_kernel(const float* __restrict__ k,
                                const float* __restrict__ v,
                                const float* __restrict__ time_decay,
                                const float* __restrict__ time_first,
                                const float* __restrict__ loc_a,
                                const float* __restrict__ loc_b,
                                float* __restrict__ out,
                                int C, int NC) {
    const int HB = H / 256;
    int hb = blockIdx.x % HB;
    int c  = (blockIdx.x / HB) % NC;
    int b  = blockIdx.x / (HB * NC);
    int h  = hb * 256 + threadIdx.x;

    float ew = expf(-expf(time_decay[h]));
    float u  = time_first[h];

    size_t o = ((size_t)c * B + b) * H + h;
    float a  = loc_a[o];
    float bb = loc_b[o];

    const float* kp = k + ((size_t)b * T + (size_t)c * C) * H + h;
    const float* vp = v + ((size_t)b * T + (size_t)c * C) * H + h;
    float* op       = out + ((size_t)b * T + (size_t)c * C) * H + h;

    for (int i = 0; i < C; ++i) {
        float kk = kp[(size_t)i * H];
        float vv = vp[(size_t)i * H];
        float ek  = expf(kk);
        float euk = expf(u + kk);
        op[(size_t)i * H] = (a + euk * vv) / (bb + euk + 1e-8f);
        a  = ew * a  + ek * vv;
        bb = ew * bb + ek;
    }
}

extern "C" void kernel_launch(void* const* d_in, const int* in_sizes, int n_in,
                              void* d_out, int out_size, void* d_ws, size_t ws_size,
                              hipStream_t stream) {
    const float* k  = (const float*)d_in[0];
    const float* v  = (const float*)d_in[1];
    const float* td = (const float*)d_in[2];
    const float* tf = (const float*)d_in[3];
    float* out      = (float*)d_out;

    // pick NC (chunks) based on workspace: need 2 * B*H*NC * 4 bytes
    int NC = 64;
    while (NC > 1 && (size_t)2 * B * H * NC * sizeof(float) > ws_size) NC >>= 1;
    int C = T / NC;

    float* loc_a = (float*)d_ws;
    float* loc_b = loc_a + (size_t)B * H * NC;

    dim3 blk(256);
    dim3 grid1(B * NC * (H / 256));
    dim3 grid2((B * H) / 256);

    wkv_local_kernel<<<grid1, blk, 0, stream>>>(k, v, td, loc_a, loc_b, C, NC);
    wkv_carry_kernel<<<grid2, blk, 0, stream>>>(td, loc_a, loc_b, out, C, NC);
    wkv_emit_kernel<<<grid1, blk, 0, stream>>>(k, v, td, tf, loc_a, loc_b, out, C, NC);
}

// Round 2
// 150.338 us; speedup vs baseline: 1.0074x; 1.0074x over previous
//
#include <hip/hip_runtime.h>
#include <math.h>

#define B 4
#define T 4096
#define H 2048
#define THREADS 256
#define VEC 4          // channels per thread
#define PF 4           // timesteps per prefetch group

typedef float f4 __attribute__((ext_vector_type(4)));

// ---------------------------------------------------------------------------
// Phase 1: per-chunk local scan from zero state. Templated on chunk length C
// so the pipeline loop fully unrolls (all buffer indices compile-time).
// Thread = (b, chunk c, 4 channels). Writes locals at [(c*B+b)*H + h].
// ---------------------------------------------------------------------------
template <int C>
__global__ __launch_bounds__(THREADS)
void wkv_local_kernel(const float* __restrict__ kg,
                      const float* __restrict__ vg,
                      const float* __restrict__ time_decay,
                      float* __restrict__ loc_a,
                      float* __restrict__ loc_b,
                      int NC) {
    const int HB = H / (THREADS * VEC);          // 2
    int hb = blockIdx.x % HB;
    int c  = (blockIdx.x / HB) % NC;
    int b  = blockIdx.x / (HB * NC);
    int h  = (hb * THREADS + threadIdx.x) * VEC;

    f4 tdv = *(const f4*)(time_decay + h);
    float ew[VEC], a[VEC], bb[VEC];
#pragma unroll
    for (int q = 0; q < VEC; ++q) {
        ew[q] = expf(-expf(tdv[q]));
        a[q] = 0.0f; bb[q] = 0.0f;
    }

    const f4* kp = (const f4*)(kg + ((size_t)b * T + (size_t)c * C) * H + h);
    const f4* vp = (const f4*)(vg + ((size_t)b * T + (size_t)c * C) * H + h);
    const int S = H / VEC;                       // f4 stride per timestep

    f4 kbuf[2][PF], vbuf[2][PF];
#pragma unroll
    for (int j = 0; j < PF; ++j) { kbuf[0][j] = kp[j * S]; vbuf[0][j] = vp[j * S]; }

    constexpr int NG = C / PF;
#pragma unroll
    for (int g = 0; g < NG; ++g) {
        const int cur = g & 1, nxt = cur ^ 1;
        if (g + 1 < NG) {
#pragma unroll
            for (int j = 0; j < PF; ++j) {
                kbuf[nxt][j] = kp[((g + 1) * PF + j) * S];
                vbuf[nxt][j] = vp[((g + 1) * PF + j) * S];
            }
        }
#pragma unroll
        for (int j = 0; j < PF; ++j) {
#pragma unroll
            for (int q = 0; q < VEC; ++q) {
                float ek = expf(kbuf[cur][j][q]);
                a[q]  = ew[q] * a[q]  + ek * vbuf[cur][j][q];
                bb[q] = ew[q] * bb[q] + ek;
            }
        }
    }

    size_t o = (((size_t)c * B + b) * H + h) / VEC;
    f4 ra = {a[0], a[1], a[2], a[3]};
    f4 rb = {bb[0], bb[1], bb[2], bb[3]};
    ((f4*)loc_a)[o] = ra;
    ((f4*)loc_b)[o] = rb;
}

// ---------------------------------------------------------------------------
// Phase 2: sequential carry scan across chunks per (b,h); overwrites locals
// in place with EXCLUSIVE carries; writes final a,b states to out.
// ---------------------------------------------------------------------------
__global__ __launch_bounds__(THREADS)
void wkv_carry_kernel(const float* __restrict__ time_decay,
                      float* __restrict__ loc_a,
                      float* __restrict__ loc_b,
                      float* __restrict__ out,
                      int C, int NC) {
    int idx = blockIdx.x * THREADS + threadIdx.x;   // 0 .. B*H-1
    int b = idx / H;
    int h = idx % H;

    float ew  = expf(-expf(time_decay[h]));
    float ewC = powf(ew, (float)C);

    float Sa = 0.0f, Sb = 0.0f;
    for (int c = 0; c < NC; ++c) {
        size_t o = ((size_t)c * B + b) * H + h;
        float la = loc_a[o];
        float lb = loc_b[o];
        loc_a[o] = Sa;
        loc_b[o] = Sb;
        Sa = ewC * Sa + la;
        Sb = ewC * Sb + lb;
    }
    out[(size_t)B * T * H + (size_t)b * H + h] = Sa;
    out[(size_t)B * T * H + (size_t)B * H + (size_t)b * H + h] = Sb;
}

// ---------------------------------------------------------------------------
// Phase 3: replay each chunk from its exclusive carry, emit wkv outputs.
// Same pipelined structure as phase 1; nontemporal output stores.
// ---------------------------------------------------------------------------
template <int C>
__global__ __launch_bounds__(THREADS)
void wkv_emit_kernel(const float* __restrict__ kg,
                     const float* __restrict__ vg,
                     const float* __restrict__ time_decay,
                     const float* __restrict__ time_first,
                     const float* __restrict__ loc_a,
                     const float* __restrict__ loc_b,
                     float* __restrict__ out,
                     int NC) {
    const int HB = H / (THREADS * VEC);
    int hb = blockIdx.x % HB;
    int c  = (blockIdx.x / HB) % NC;
    int b  = blockIdx.x / (HB * NC);
    int h  = (hb * THREADS + threadIdx.x) * VEC;

    f4 tdv = *(const f4*)(time_decay + h);
    f4 tfv = *(const f4*)(time_first + h);
    float ew[VEC], eu[VEC], a[VEC], bb[VEC];

    size_t o = (((size_t)c * B + b) * H + h) / VEC;
    f4 ca = ((const f4*)loc_a)[o];
    f4 cb = ((const f4*)loc_b)[o];
#pragma unroll
    for (int q = 0; q < VEC; ++q) {
        ew[q] = expf(-expf(tdv[q]));
        eu[q] = expf(tfv[q]);
        a[q] = ca[q]; bb[q] = cb[q];
    }

    const f4* kp = (const f4*)(kg + ((size_t)b * T + (size_t)c * C) * H + h);
    const f4* vp = (const f4*)(vg + ((size_t)b * T + (size_t)c * C) * H + h);
    f4* op       = (f4*)(out + ((size_t)b * T + (size_t)c * C) * H + h);
    const int S = H / VEC;

    f4 kbuf[2][PF], vbuf[2][PF];
#pragma unroll
    for (int j = 0; j < PF; ++j) { kbuf[0][j] = kp[j * S]; vbuf[0][j] = vp[j * S]; }

    constexpr int NG = C / PF;
#pragma unroll
    for (int g = 0; g < NG; ++g) {
        const int cur = g & 1, nxt = cur ^ 1;
        if (g + 1 < NG) {
#pragma unroll
            for (int j = 0; j < PF; ++j) {
                kbuf[nxt][j] = kp[((g + 1) * PF + j) * S];
                vbuf[nxt][j] = vp[((g + 1) * PF + j) * S];
            }
        }
#pragma unroll
        for (int j = 0; j < PF; ++j) {
            f4 r;
#pragma unroll
            for (int q = 0; q < VEC; ++q) {
                float kk  = kbuf[cur][j][q];
                float vv  = vbuf[cur][j][q];
                float ek  = expf(kk);
                float euk = ek * eu[q];
                r[q] = (a[q] + euk * vv) / (bb[q] + euk + 1e-8f);
                a[q]  = ew[q] * a[q]  + ek * vv;
                bb[q] = ew[q] * bb[q] + ek;
            }
            __builtin_nontemporal_store(r, op + (size_t)(g * PF + j) * S);
        }
    }
}

extern "C" void kernel_launch(void* const* d_in, const int* in_sizes, int n_in,
                              void* d_out, int out_size, void* d_ws, size_t ws_size,
                              hipStream_t stream) {
    const float* k  = (const float*)d_in[0];
    const float* v  = (const float*)d_in[1];
    const float* td = (const float*)d_in[2];
    const float* tf = (const float*)d_in[3];
    float* out      = (float*)d_out;

    int NC = 128;                                    // C = 32
    if ((size_t)2 * B * H * NC * sizeof(float) > ws_size) NC = 64;  // C = 64 (proven fit)
    int C = T / NC;

    float* loc_a = (float*)d_ws;
    float* loc_b = loc_a + (size_t)B * H * NC;

    dim3 blk(THREADS);
    dim3 grid1(B * NC * (H / (THREADS * VEC)));
    dim3 grid2((B * H) / THREADS);

    if (NC == 128) {
        wkv_local_kernel<32><<<grid1, blk, 0, stream>>>(k, v, td, loc_a, loc_b, NC);
        wkv_carry_kernel<<<grid2, blk, 0, stream>>>(td, loc_a, loc_b, out, C, NC);
        wkv_emit_kernel<32><<<grid1, blk, 0, stream>>>(k, v, td, tf, loc_a, loc_b, out, NC);
    } else {
        wkv_local_kernel<64><<<grid1, blk, 0, stream>>>(k, v, td, loc_a, loc_b, NC);
        wkv_carry_kernel<<<grid2, blk, 0, stream>>>(td, loc_a, loc_b, out, C, NC);
        wkv_emit_kernel<64><<<grid1, blk, 0, stream>>>(k, v, td, tf, loc_a, loc_b, out, NC);
    }
}

// Round 3
// 120.585 us; speedup vs baseline: 1.2560x; 1.2467x over previous
//
#include <hip/hip_runtime.h>
#include <math.h>
#include <stdint.h>

#define B 4
#define T 4096
#define H 2048
#define NC 128
#define C  (T / NC)        // 32 timesteps per chunk
#define SR 8               // timesteps per stage
#define NS (C / SR)        // 4 stages per chunk
#define THREADS 256

typedef const __attribute__((address_space(1))) uint32_t* gas_ptr;
typedef __attribute__((address_space(3))) uint32_t* las_ptr;

// One wave stages one 256-float row (1 KB): lane l supplies bytes [16l,16l+16),
// HW writes LDS at (uniform base) + lane*16 — linear, matching global layout.
__device__ __forceinline__ void stage_row(const float* grow, float* lrow, int lane) {
    __builtin_amdgcn_global_load_lds((gas_ptr)(const void*)(grow + lane * 4),
                                     (las_ptr)(void*)lrow, 16, 0, 0);
}

// ---------------------------------------------------------------------------
// Phase 1: per-chunk local scan from zero state.
// grid: B*NC*(H/256) blocks. Block = (b, chunk c, 256-channel band hb).
// ---------------------------------------------------------------------------
__global__ __launch_bounds__(THREADS)
void wkv_local_kernel(const float* __restrict__ kg,
                      const float* __restrict__ vg,
                      const float* __restrict__ time_decay,
                      float* __restrict__ loc_a,
                      float* __restrict__ loc_b) {
    __shared__ float lk[2][SR][256];
    __shared__ float lv[2][SR][256];

    int hb = blockIdx.x & 7;                 // H/256 = 8
    int c  = (blockIdx.x >> 3) & (NC - 1);
    int b  = blockIdx.x >> 3 >> 7;           // / (8*NC)
    int tid  = threadIdx.x;
    int lane = tid & 63;
    int wv   = tid >> 6;                     // wave id 0..3; stages rows 2wv,2wv+1

    const float* kbase = kg + ((size_t)b * T + (size_t)c * C) * H + hb * 256;
    const float* vbase = vg + ((size_t)b * T + (size_t)c * C) * H + hb * 256;

    float ew = expf(-expf(time_decay[hb * 256 + tid]));
    float a = 0.0f, bb = 0.0f;

#define ISSUE(s, bufi)                                                        \
    {                                                                         \
        _Pragma("unroll")                                                     \
        for (int j = 0; j < 2; ++j) {                                         \
            int r = 2 * wv + j;                                               \
            stage_row(kbase + (size_t)((s) * SR + r) * H, &lk[bufi][r][0], lane); \
            stage_row(vbase + (size_t)((s) * SR + r) * H, &lv[bufi][r][0], lane); \
        }                                                                     \
    }

    ISSUE(0, 0);
#pragma unroll
    for (int s = 0; s < NS; ++s) {
        const int cur = s & 1;
        if (s + 1 < NS) {
            ISSUE(s + 1, cur ^ 1);
            asm volatile("s_waitcnt vmcnt(4)" ::: "memory");   // stage s done; s+1 in flight
        } else {
            asm volatile("s_waitcnt vmcnt(0)" ::: "memory");
        }
        __builtin_amdgcn_s_barrier();
#pragma unroll
        for (int t = 0; t < SR; ++t) {
            float kk = lk[cur][t][tid];
            float vv = lv[cur][t][tid];
            float ek = expf(kk);
            a  = ew * a  + ek * vv;
            bb = ew * bb + ek;
        }
        __builtin_amdgcn_s_barrier();        // all reads done before buf reuse
    }

    size_t o = ((size_t)c * B + b) * H + hb * 256 + tid;
    loc_a[o] = a;
    loc_b[o] = bb;
}

// ---------------------------------------------------------------------------
// Phase 2: carry scan across chunks per (b,h); locals -> exclusive carries;
// final states to out.
// ---------------------------------------------------------------------------
__global__ __launch_bounds__(THREADS)
void wkv_carry_kernel(const float* __restrict__ time_decay,
                      float* __restrict__ loc_a,
                      float* __restrict__ loc_b,
                      float* __restrict__ out) {
    int idx = blockIdx.x * THREADS + threadIdx.x;   // 0 .. B*H-1
    int b = idx / H;
    int h = idx % H;

    float ew  = expf(-expf(time_decay[h]));
    float ewC = powf(ew, (float)C);

    float Sa = 0.0f, Sb = 0.0f;
    for (int c = 0; c < NC; ++c) {
        size_t o = ((size_t)c * B + b) * H + h;
        float la = loc_a[o];
        float lb = loc_b[o];
        loc_a[o] = Sa;
        loc_b[o] = Sb;
        Sa = ewC * Sa + la;
        Sb = ewC * Sb + lb;
    }
    out[(size_t)B * T * H + (size_t)b * H + h] = Sa;
    out[(size_t)B * T * H + (size_t)B * H + (size_t)b * H + h] = Sb;
}

// ---------------------------------------------------------------------------
// Phase 3: replay each chunk from its exclusive carry, emit wkv outputs.
// Same staged structure; nontemporal coalesced output stores.
// ---------------------------------------------------------------------------
__global__ __launch_bounds__(THREADS)
void wkv_emit_kernel(const float* __restrict__ kg,
                     const float* __restrict__ vg,
                     const float* __restrict__ time_decay,
                     const float* __restrict__ time_first,
                     const float* __restrict__ loc_a,
                     const float* __restrict__ loc_b,
                     float* __restrict__ out) {
    __shared__ float lk[2][SR][256];
    __shared__ float lv[2][SR][256];

    int hb = blockIdx.x & 7;
    int c  = (blockIdx.x >> 3) & (NC - 1);
    int b  = blockIdx.x >> 3 >> 7;
    int tid  = threadIdx.x;
    int lane = tid & 63;
    int wv   = tid >> 6;

    const float* kbase = kg + ((size_t)b * T + (size_t)c * C) * H + hb * 256;
    const float* vbase = vg + ((size_t)b * T + (size_t)c * C) * H + hb * 256;
    float* obase       = out + ((size_t)b * T + (size_t)c * C) * H + hb * 256;

    int h = hb * 256 + tid;
    float ew = expf(-expf(time_decay[h]));
    float eu = expf(time_first[h]);

    size_t o = ((size_t)c * B + b) * H + h;
    float a  = loc_a[o];
    float bb = loc_b[o];

    ISSUE(0, 0);
#pragma unroll
    for (int s = 0; s < NS; ++s) {
        const int cur = s & 1;
        if (s + 1 < NS) {
            ISSUE(s + 1, cur ^ 1);
            asm volatile("s_waitcnt vmcnt(4)" ::: "memory");
        } else {
            asm volatile("s_waitcnt vmcnt(0)" ::: "memory");
        }
        __builtin_amdgcn_s_barrier();
#pragma unroll
        for (int t = 0; t < SR; ++t) {
            float kk  = lk[cur][t][tid];
            float vv  = lv[cur][t][tid];
            float ek  = expf(kk);
            float euk = ek * eu;
            float r   = (a + euk * vv) / (bb + euk + 1e-8f);
            __builtin_nontemporal_store(r, obase + (size_t)(s * SR + t) * H + tid);
            a  = ew * a  + ek * vv;
            bb = ew * bb + ek;
        }
        __builtin_amdgcn_s_barrier();
    }
}

extern "C" void kernel_launch(void* const* d_in, const int* in_sizes, int n_in,
                              void* d_out, int out_size, void* d_ws, size_t ws_size,
                              hipStream_t stream) {
    const float* k  = (const float*)d_in[0];
    const float* v  = (const float*)d_in[1];
    const float* td = (const float*)d_in[2];
    const float* tf = (const float*)d_in[3];
    float* out      = (float*)d_out;

    float* loc_a = (float*)d_ws;                       // needs 8 MB total (fits: round-2 proven)
    float* loc_b = loc_a + (size_t)B * H * NC;

    dim3 blk(THREADS);
    dim3 grid1(B * NC * (H / 256));                    // 4096 blocks
    dim3 grid2((B * H) / THREADS);                     // 32 blocks

    wkv_local_kernel<<<grid1, blk, 0, stream>>>(k, v, td, loc_a, loc_b);
    wkv_carry_kernel<<<grid2, blk, 0, stream>>>(td, loc_a, loc_b, out);
    wkv_emit_kernel<<<grid1, blk, 0, stream>>>(k, v, td, tf, loc_a, loc_b, out);
}